// Round 1
// baseline (830.003 us; speedup 1.0000x reference)
//
#include <hip/hip_runtime.h>
#include <math.h>

// ---------------------------------------------------------------------------
// GraphProjection: project N=65536 points into V=3 camera views, gather
// multi-scale CNN features (batch index faithfully truncates to 0), reduce
// max/mean/biased-std over views. Output [N, 3 + 3*960] f32.
//
// Memory plan: output write (756 MB) dominates -> main kernel must be
// write-coalesced. Feature tables (batch 0 only, 1.5 MB) are transposed to
// [H,W,C] in d_ws so per-point channel gathers are contiguous.
// Geometry computed in double to track the high-precision reference (index
// truncation is flip-sensitive); per-channel stats in f32 (flip-insensitive).
// ---------------------------------------------------------------------------

#define TBL_TOTAL 376320            // 56*56*64 + 28*28*128 + 14*14*256 + 7*7*512
#define TBL_OFF0  0
#define TBL_OFF1  200704
#define TBL_OFF2  301056
#define TBL_OFF3  351232

__device__ __forceinline__ void compute_cams(const float* __restrict__ cams,
                                             double M[3][3], double o0[3],
                                             double cm[3][3][3], double om[3][3]) {
  // PI is np.float32(np.pi) in the reference; PI/180 stays f32-rounded.
  const double DEG  = (double)(3.14159274101257324f / 180.0f);
  const double PI_D = (double)3.14159274101257324f;
  for (int v = 0; v < 3; ++v) {
    double th = (double)cams[v * 5 + 0] * DEG;
    double ph = (double)cams[v * 5 + 1] * DEG;
    double dd = (double)cams[v * 5 + 3];
    double camy = dd * sin(ph);
    double lens = dd * cos(ph);
    double camx = lens * cos(th);
    double camz = lens * sin(th);
    double Zx = camx, Zy = camy, Zz = camz;
    double Yx = camy * cos(th + PI_D), Yy = lens, Yz = camy * sin(th + PI_D);
    double Xx = Yy * Zz - Yz * Zy;
    double Xy = Yz * Zx - Yx * Zz;
    double Xz = Yx * Zy - Yy * Zx;
    double nX = sqrt(Xx * Xx + Xy * Xy + Xz * Xz);
    double nY = sqrt(Yx * Yx + Yy * Yy + Yz * Yz);
    double nZ = sqrt(Zx * Zx + Zy * Zy + Zz * Zz);
    cm[v][0][0] = Xx / nX; cm[v][0][1] = Xy / nX; cm[v][0][2] = Xz / nX;
    cm[v][1][0] = Yx / nY; cm[v][1][1] = Yy / nY; cm[v][1][2] = Yz / nY;
    cm[v][2][0] = Zx / nZ; cm[v][2][1] = Zy / nZ; cm[v][2][2] = Zz / nZ;
    om[v][0] = Zx; om[v][1] = Zy; om[v][2] = Zz;
  }
  // A = c0^T ; M = inv(A) via adjugate (double precision).
  double a00 = cm[0][0][0], a01 = cm[0][1][0], a02 = cm[0][2][0];
  double a10 = cm[0][0][1], a11 = cm[0][1][1], a12 = cm[0][2][1];
  double a20 = cm[0][0][2], a21 = cm[0][1][2], a22 = cm[0][2][2];
  double det = a00 * (a11 * a22 - a12 * a21)
             - a01 * (a10 * a22 - a12 * a20)
             + a02 * (a10 * a21 - a11 * a20);
  M[0][0] = (a11 * a22 - a12 * a21) / det;
  M[0][1] = (a02 * a21 - a01 * a22) / det;
  M[0][2] = (a01 * a12 - a02 * a11) / det;
  M[1][0] = (a12 * a20 - a10 * a22) / det;
  M[1][1] = (a00 * a22 - a02 * a20) / det;
  M[1][2] = (a02 * a10 - a00 * a12) / det;
  M[2][0] = (a10 * a21 - a11 * a20) / det;
  M[2][1] = (a01 * a20 - a00 * a21) / det;
  M[2][2] = (a00 * a11 - a01 * a10) / det;
  o0[0] = om[0][0]; o0[1] = om[0][1]; o0[2] = om[0][2];
}

// Tiny setup kernel: camera params -> 48 doubles in workspace.
// Layout: M[9] | o0[3] | c[3][3][3] (27) | o[3][3] (9)
__global__ void k_setup(const float* __restrict__ cams, double* __restrict__ P) {
  if (threadIdx.x != 0 || blockIdx.x != 0) return;
  double M[3][3], o0[3], cm[3][3][3], om[3][3];
  compute_cams(cams, M, o0, cm, om);
  int i = 0;
  for (int r = 0; r < 3; ++r)
    for (int k = 0; k < 3; ++k) P[i++] = M[r][k];
  for (int k = 0; k < 3; ++k) P[i++] = o0[k];
  for (int v = 0; v < 3; ++v)
    for (int r = 0; r < 3; ++r)
      for (int k = 0; k < 3; ++k) P[i++] = cm[v][r][k];
  for (int v = 0; v < 3; ++v)
    for (int k = 0; k < 3; ++k) P[i++] = om[v][k];
}

// Transpose batch 0 of each feature level from [C,H,W] -> [H*W, C].
__global__ void k_transpose(const float* __restrict__ f0, const float* __restrict__ f1,
                            const float* __restrict__ f2, const float* __restrict__ f3,
                            float* __restrict__ tbl) {
  int i = blockIdx.x * 256 + threadIdx.x;
  if (i >= TBL_TOTAL) return;
  const float* src;
  int j, cmask, clog, HW;
  if (i < TBL_OFF1)      { src = f0; j = i;            cmask = 63;  clog = 6; HW = 3136; }
  else if (i < TBL_OFF2) { src = f1; j = i - TBL_OFF1; cmask = 127; clog = 7; HW = 784;  }
  else if (i < TBL_OFF3) { src = f2; j = i - TBL_OFF2; cmask = 255; clog = 8; HW = 196;  }
  else                   { src = f3; j = i - TBL_OFF3; cmask = 511; clog = 9; HW = 49;   }
  int c  = j & cmask;
  int hw = j >> clog;
  tbl[i] = src[c * HW + hw];   // batch 0 only (faithful truncated batch index)
}

template <bool TRANSPOSED>
__global__ __launch_bounds__(256) void k_main(
    const float* __restrict__ inpts, const float* __restrict__ cams,
    const double* __restrict__ P, const float* __restrict__ tbl,
    const float* __restrict__ f0, const float* __restrict__ f1,
    const float* __restrict__ f2, const float* __restrict__ f3,
    float* __restrict__ out) {
  __shared__ int s_off[3][4];
  const int p = blockIdx.x;
  const int tid = threadIdx.x;

  if (tid < 3) {
    const int v = tid;
    double M[3][3], o0[3], cmv[3][3], ovv[3];
    if (TRANSPOSED) {
      M[0][0] = P[0]; M[0][1] = P[1]; M[0][2] = P[2];
      M[1][0] = P[3]; M[1][1] = P[4]; M[1][2] = P[5];
      M[2][0] = P[6]; M[2][1] = P[7]; M[2][2] = P[8];
      o0[0] = P[9]; o0[1] = P[10]; o0[2] = P[11];
      for (int r = 0; r < 3; ++r)
        for (int k = 0; k < 3; ++k) cmv[r][k] = P[12 + v * 9 + r * 3 + k];
      ovv[0] = P[39 + v * 3 + 0]; ovv[1] = P[39 + v * 3 + 1]; ovv[2] = P[39 + v * 3 + 2];
    } else {
      double cm[3][3][3], om[3][3];
      compute_cams(cams, M, o0, cm, om);
      for (int r = 0; r < 3; ++r)
        for (int k = 0; k < 3; ++k) cmv[r][k] = cm[v][r][k];
      ovv[0] = om[v][0]; ovv[1] = om[v][1]; ovv[2] = om[v][2];
    }
    double x = (double)inpts[p * 3 + 0];
    double y = (double)inpts[p * 3 + 1];
    double z = (double)inpts[p * 3 + 2];
    // point_origin = inputs @ inv(c0^T) + o0
    double p0 = x * M[0][0] + y * M[1][0] + z * M[2][0] + o0[0];
    double p1 = x * M[0][1] + y * M[1][1] + z * M[2][1] + o0[1];
    double p2 = x * M[0][2] + y * M[1][2] + z * M[2][2] + o0[2];
    double q0 = p0 - ovv[0], q1 = p1 - ovv[1], q2 = p2 - ovv[2];
    double Xc = q0 * cmv[0][0] + q1 * cmv[0][1] + q2 * cmv[0][2];
    double Yc = q0 * cmv[1][0] + q1 * cmv[1][1] + q2 * cmv[1][2];
    double Zc = q0 * cmv[2][0] + q1 * cmv[2][1] + q2 * cmv[2][2];
    double nz = -Zc;
    double hv = 248.0 * (-Yc) / nz + 112.0;
    double wv = 248.0 * Xc / nz + 112.0;
    if (isnan(hv)) hv = 0.0;
    if (isnan(wv)) wv = 0.0;
    hv = fmin(fmax(hv, 0.0), 223.0);
    wv = fmin(fmax(wv, 0.0), 223.0);
    // scales 224/size = {4,8,16,32} are exact powers of two
    int h0 = (int)(hv * 0.25),    w0 = (int)(wv * 0.25);
    int h1 = (int)(hv * 0.125),   w1 = (int)(wv * 0.125);
    int h2 = (int)(hv * 0.0625),  w2 = (int)(wv * 0.0625);
    int h3 = (int)(hv * 0.03125), w3 = (int)(wv * 0.03125);
    if (TRANSPOSED) {
      s_off[v][0] = TBL_OFF0 + (h0 * 56 + w0) * 64;
      s_off[v][1] = TBL_OFF1 + (h1 * 28 + w1) * 128;
      s_off[v][2] = TBL_OFF2 + (h2 * 14 + w2) * 256;
      s_off[v][3] = TBL_OFF3 + (h3 * 7  + w3) * 512;
    } else {
      s_off[v][0] = h0 * 56 + w0;
      s_off[v][1] = h1 * 28 + w1;
      s_off[v][2] = h2 * 14 + w2;
      s_off[v][3] = h3 * 7  + w3;
    }
    out[p * 2883 + v] = inpts[p * 3 + v];   // passthrough xyz
  }
  __syncthreads();

  const int row = p * 2883;
  for (int c = tid; c < 960; c += 256) {
    int l, cl;
    if (c < 64)       { l = 0; cl = c; }
    else if (c < 192) { l = 1; cl = c - 64; }
    else if (c < 448) { l = 2; cl = c - 192; }
    else              { l = 3; cl = c - 448; }
    float v0, v1, v2;
    if (TRANSPOSED) {
      v0 = tbl[s_off[0][l] + cl];
      v1 = tbl[s_off[1][l] + cl];
      v2 = tbl[s_off[2][l] + cl];
    } else {
      const float* f = (l == 0) ? f0 : (l == 1) ? f1 : (l == 2) ? f2 : f3;
      const int HW   = (l == 0) ? 3136 : (l == 1) ? 784 : (l == 2) ? 196 : 49;
      v0 = f[cl * HW + s_off[0][l]];
      v1 = f[cl * HW + s_off[1][l]];
      v2 = f[cl * HW + s_off[2][l]];
    }
    float mx = fmaxf(fmaxf(v0, v1), v2);
    float sm = (v0 + v1) + v2;
    float mean = sm / 3.0f;
    float d0 = v0 - mean, d1 = v1 - mean, d2 = v2 - mean;
    float var = ((d0 * d0 + d1 * d1) + d2 * d2) / 3.0f;
    float sd = sqrtf(var);
    out[row + 3 + c]    = mx;
    out[row + 963 + c]  = mean;
    out[row + 1923 + c] = sd;
  }
}

extern "C" void kernel_launch(void* const* d_in, const int* in_sizes, int n_in,
                              void* d_out, int out_size, void* d_ws, size_t ws_size,
                              hipStream_t stream) {
  const float* inpts = (const float*)d_in[0];
  const float* cams  = (const float*)d_in[1];
  const float* f0    = (const float*)d_in[2];
  const float* f1    = (const float*)d_in[3];
  const float* f2    = (const float*)d_in[4];
  const float* f3    = (const float*)d_in[5];
  float* out = (float*)d_out;
  const int N = in_sizes[0] / 3;

  const size_t TBL_BYTE_OFF = 512;
  const size_t NEED = TBL_BYTE_OFF + (size_t)TBL_TOTAL * sizeof(float);

  if (ws_size >= NEED) {
    double* P  = (double*)d_ws;
    float* tbl = (float*)((char*)d_ws + TBL_BYTE_OFF);
    k_setup<<<1, 64, 0, stream>>>(cams, P);
    k_transpose<<<(TBL_TOTAL + 255) / 256, 256, 0, stream>>>(f0, f1, f2, f3, tbl);
    k_main<true><<<N, 256, 0, stream>>>(inpts, cams, P, tbl, f0, f1, f2, f3, out);
  } else {
    // Fallback: no workspace -> inline camera math, direct (uncoalesced) gather.
    k_main<false><<<N, 256, 0, stream>>>(inpts, cams, nullptr, nullptr, f0, f1, f2, f3, out);
  }
}